// Round 4
// baseline (215.670 us; speedup 1.0000x reference)
//
#include <hip/hip_runtime.h>
#include <math.h>

#define UNITS 64
#define TT 100
#define NB 32          // TWO 16-row MFMA M-tiles per block (r18)
#define NTH 256        // 4 waves; wave w owns unit-columns [16w,16w+16) for all 4 gates
#define HSTR 72        // hbuf row stride in halves (identity rows: b128 reads 2-way = free)
#define XQSTR 34       // xt quad stride per timestep (32 rows + 2 pad)

typedef _Float16 half8 __attribute__((ext_vector_type(8)));
typedef _Float16 half4 __attribute__((ext_vector_type(4)));
typedef float floatx4 __attribute__((ext_vector_type(4)));

#define LOG2E 1.44269504088896f

__device__ __forceinline__ float rcp_fast(float x) { return __builtin_amdgcn_rcpf(x); }
__device__ __forceinline__ float exp2_fast(float x) { return __builtin_amdgcn_exp2f(x); }

// Session ledger (key structural facts, do not re-derive):
//  - ONE dispatch total: extra graph nodes cost 30-75 us; cross-block sync 300-1300 us.
//  - length-sorting / load-balancing structurally dead (exactly-resident grid).
//  - r16 (8 waves via launch_bounds(512,8)) FAILED: VGPR cap 64 -> Bf spilled ->
//    1.5 GB HBM, 731 us. 4-gate-complete layout needs ~91+ VGPR.
//  - hslot write-permutation moved conflicts writes->reads, net zero. Write
//    conflicts (~3.6M cyc, ~4%) accepted; reads must stay clean.
//  - r17 recalibration: f32 trans (exp2/rcp) issue ~16 cyc/wave64 (1/8 rate!),
//    not 8. Trans ~58% of wall; ~35% of wall is non-issue idle (latency/barrier).
// Round 18 (this round):
//  - NB=32: two M-tiles per block, same 4 waves -> 2x per-wave ILP (8 independent
//    activation chains feed the 1/8-rate trans pipe through its latency), half
//    the barriers per work. Grid 512 -> 2 blocks/CU, 2 waves/SIMD.
//    launch_bounds(256,2): VGPR cap 256, est ~140-170 -> NO spill (verify!).
//  - merged recurrence rcp (8 -> 7 trans/cell):
//      dn = (d*P + tg*Af) * rcp(Af*P),  P=(1+ei)(1+eg), Af=(1+ef),
//      tg=-2L(1-eg);  then ed=exp2(min(dn,80)), hv=(1-ed)*rcp((1+eo)(1+ed)).
//    Clamp 80 (not 126): Q <= 2^80 * 2^43 < 2^127, no overflow; exact at
//    saturation (tanh=-1 region).
__global__ __launch_bounds__(NTH, 2) void lstm_kernel(
    const float* __restrict__ x,    // (B,100,3)
    const float* __restrict__ W,    // (3,256)
    const float* __restrict__ U,    // (64,256)
    const float* __restrict__ bias, // (256,)
    const float* __restrict__ W1,   // (64,64)
    const float* __restrict__ b1,   // (64,)
    const float* __restrict__ W2,   // (64,5)
    const float* __restrict__ b2,   // (5,)
    float* __restrict__ out, int B)
{
    __shared__ __align__(16) _Float16 hb[2][NB * HSTR];   // double-buffered h (f16), 32 rows
    __shared__ __align__(16) _Float16 xt[TT * XQSTR * 4]; // staged x tile: quads {x0,x1,x2,1}
    __shared__ int llen_s[NB];                            // per-row lengths (this tile)
    __shared__ float h1buf[NB * 64];
    __shared__ float logitbuf[NB * 5];

    const int tid = threadIdx.x;
    const int w   = tid >> 6;
    const int l   = tid & 63;
    const int q   = l >> 4;
    const int cnl = l & 15;
    const int b0  = blockIdx.x * NB;

    // ---- in-block per-row lengths: 8 lanes/row over 32 rows ----
    {
        const int grp8 = tid >> 3;        // row 0..31
        const int sub8 = tid & 7;
        const float* xp = x + (size_t)(b0 + grp8) * (TT * 3);
        int m = 0;
        for (int t = sub8; t < TT; t += 8) {
            const float a = xp[3*t], b = xp[3*t+1], c = xp[3*t+2];
            if (a != 0.0f || b != 0.0f || c != 0.0f) m = t + 1;
        }
        #pragma unroll
        for (int off = 4; off; off >>= 1) m = max(m, __shfl_down(m, off, 8));
        if (sub8 == 0) llen_s[grp8] = m;
    }
    for (int i = tid; i < NB * HSTR; i += NTH) hb[0][i] = (_Float16)0.0f;
    __syncthreads();   // llen_s visible before ANY reader

    int maxlen = 0, minlen = TT;
    #pragma unroll
    for (int i = 0; i < NB; ++i) {             // LDS broadcast reads, cheap
        const int v = llen_s[i];
        maxlen = max(maxlen, v);
        minlen = min(minlen, v);
    }
    maxlen = (maxlen < 0) ? 0 : ((maxlen > TT) ? TT : maxlen);
    minlen = (minlen < 0) ? 0 : ((minlen > maxlen) ? maxlen : minlen);
    int rlA[4], rlB[4];
    #pragma unroll
    for (int r = 0; r < 4; ++r) { rlA[r] = llen_s[4*q + r]; rlB[r] = llen_s[16 + 4*q + r]; }

    // ---- stage x tile as f16 quads {x0,x1,x2,1}, 8 lanes/row ----
    {
        const int grp8 = tid >> 3;
        const int sub8 = tid & 7;
        const float* xp = x + (size_t)(b0 + grp8) * (TT * 3);
        for (int t = sub8; t < maxlen; t += 8) {
            const float a = xp[3*t], b = xp[3*t+1], c = xp[3*t+2];
            half4 v = { (_Float16)a, (_Float16)b, (_Float16)c, (_Float16)1.0f };
            *(half4*)&xt[(t * XQSTR + grp8) * 4] = v;
        }
    }

    // ---- extended-K B fragments: rows 0..63=U, 64..66=W, 67=bias, 68..95=0.
    // PRESCALED: i,f,o columns by -LOG2E, g columns by -2*LOG2E.
    half8 Bf[4][3];
    {
        const float gscale[4] = { -LOG2E, -LOG2E, -2.0f * LOG2E, -LOG2E };
        #pragma unroll
        for (int g = 0; g < 4; ++g) {
            const int zc = 64 * g + 16 * w + cnl;
            #pragma unroll
            for (int kb = 0; kb < 3; ++kb)
                #pragma unroll
                for (int j = 0; j < 8; ++j) {
                    const int k = 32 * kb + 8 * q + j;
                    float v = 0.0f;
                    if (k < 64)       v = U[k * 256 + zc];
                    else if (k < 67)  v = W[(k - 64) * 256 + zc];
                    else if (k == 67) v = bias[zc];
                    Bf[g][kb][j] = (_Float16)(v * gscale[g]);
                }
        }
    }

    // cell state in scaled domain d = -2*LOG2E*c ; slots 0..3 tile A, 4..7 tile B
    float d4[8] = {0,0,0,0,0,0,0,0};
    _Float16 hcur[8] = {(_Float16)0.0f,(_Float16)0.0f,(_Float16)0.0f,(_Float16)0.0f,
                        (_Float16)0.0f,(_Float16)0.0f,(_Float16)0.0f,(_Float16)0.0f};
    const floatx4 zero4 = {0.0f, 0.0f, 0.0f, 0.0f};

    const int rslA = cnl * HSTR;             // tile A rows 0..15
    const int rslB = (16 + cnl) * HSTR;      // tile B rows 16..31
    int wrA[4], wrB[4];
    #pragma unroll
    for (int r = 0; r < 4; ++r) {
        wrA[r] = (4*q + r) * HSTR + 16*w + cnl;
        wrB[r] = (16 + 4*q + r) * HSTR + 16*w + cnl;
    }

    __syncthreads();   // staging + hb[0] zero visible

// 7-trans cell update. ACC = acc row (compile-time), S = state slot, WRV = write addr
#define CELL_BODY(ACCV, RR, S, WRV)                                           \
    {                                                                         \
        const float ei = exp2_fast(ACCV[0][RR]);                              \
        const float ef = exp2_fast(ACCV[1][RR]);                              \
        const float eg = exp2_fast(ACCV[2][RR]);                              \
        const float eo = exp2_fast(ACCV[3][RR]);                              \
        const float Ag = 1.0f + eg;                                           \
        const float P  = __builtin_fmaf(ei, Ag, Ag);         /* (1+ei)(1+eg) */ \
        const float Af = 1.0f + ef;                                           \
        const float R  = P * Af;                                              \
        const float tg = __builtin_fmaf(2.0f*LOG2E, eg, -2.0f*LOG2E);         \
        const float nm = __builtin_fmaf(d4[S], P, tg * Af);                   \
        const float dn = nm * rcp_fast(R);                                    \
        d4[S] = dn;                                                           \
        const float ed = exp2_fast(fminf(dn, 80.0f));                         \
        const float D2 = 1.0f + ed;                                           \
        const float Q  = __builtin_fmaf(eo, D2, D2);         /* (1+eo)(1+ed) */ \
        const float hv = (1.0f - ed) * rcp_fast(Q);                           \
        hcur[S] = (_Float16)hv;                                               \
        hbn[WRV] = hcur[S];                                                   \
    }

#define CELL_BODY_MASK(ACCV, RR, S, WRV, LEN)                                 \
    {                                                                         \
        const bool live = (t < LEN);                                          \
        const float ei = exp2_fast(ACCV[0][RR]);                              \
        const float ef = exp2_fast(ACCV[1][RR]);                              \
        const float eg = exp2_fast(ACCV[2][RR]);                              \
        const float eo = exp2_fast(ACCV[3][RR]);                              \
        const float Ag = 1.0f + eg;                                           \
        const float P  = __builtin_fmaf(ei, Ag, Ag);                          \
        const float Af = 1.0f + ef;                                           \
        const float R  = P * Af;                                              \
        const float tg = __builtin_fmaf(2.0f*LOG2E, eg, -2.0f*LOG2E);         \
        const float nm = __builtin_fmaf(d4[S], P, tg * Af);                   \
        const float dn = nm * rcp_fast(R);                                    \
        d4[S] = live ? dn : d4[S];                                            \
        const float ed = exp2_fast(fminf(dn, 80.0f));                         \
        const float D2 = 1.0f + ed;                                           \
        const float Q  = __builtin_fmaf(eo, D2, D2);                          \
        const float hv = (1.0f - ed) * rcp_fast(Q);                           \
        const _Float16 hn = (_Float16)hv;                                     \
        hcur[S] = live ? hn : hcur[S];                                        \
        hbn[WRV] = hcur[S];                                                   \
    }

    int t = 0;

    // ---- unmasked main loop: all 32 rows live for t < minlen ----
    #pragma unroll 1
    for (; t < minlen; ++t) {
        const _Float16* hbc = hb[t & 1];
        _Float16*       hbn = hb[(t + 1) & 1];

        const half8 A0a = *(const half8*)&hbc[rslA + 8 * q];
        const half8 A1a = *(const half8*)&hbc[rslA + 32 + 8 * q];
        const half8 A0b = *(const half8*)&hbc[rslB + 8 * q];
        const half8 A1b = *(const half8*)&hbc[rslB + 32 + 8 * q];
        const half4 x4a = *(const half4*)&xt[(t * XQSTR + cnl) * 4];
        const half4 x4b = *(const half4*)&xt[(t * XQSTR + 16 + cnl) * 4];
        const half8 AXa = { x4a[0], x4a[1], x4a[2], x4a[3],
                            (_Float16)0.0f, (_Float16)0.0f, (_Float16)0.0f, (_Float16)0.0f };
        const half8 AXb = { x4b[0], x4b[1], x4b[2], x4b[3],
                            (_Float16)0.0f, (_Float16)0.0f, (_Float16)0.0f, (_Float16)0.0f };

        floatx4 accA[4], accB[4];
        #pragma unroll
        for (int g = 0; g < 4; ++g) {
            accA[g] = __builtin_amdgcn_mfma_f32_16x16x32_f16(AXa, Bf[g][2], zero4, 0, 0, 0);
            accB[g] = __builtin_amdgcn_mfma_f32_16x16x32_f16(AXb, Bf[g][2], zero4, 0, 0, 0);
            accA[g] = __builtin_amdgcn_mfma_f32_16x16x32_f16(A0a, Bf[g][0], accA[g], 0, 0, 0);
            accB[g] = __builtin_amdgcn_mfma_f32_16x16x32_f16(A0b, Bf[g][0], accB[g], 0, 0, 0);
            accA[g] = __builtin_amdgcn_mfma_f32_16x16x32_f16(A1a, Bf[g][1], accA[g], 0, 0, 0);
            accB[g] = __builtin_amdgcn_mfma_f32_16x16x32_f16(A1b, Bf[g][1], accB[g], 0, 0, 0);
        }

        #pragma unroll
        for (int r = 0; r < 4; ++r) {
            CELL_BODY(accA, r, r, wrA[r])
            CELL_BODY(accB, r, (4 + r), wrB[r])
        }
        __syncthreads();
    }

    // ---- masked tail: rows die as t reaches their length ----
    #pragma unroll 1
    for (; t < maxlen; ++t) {
        const _Float16* hbc = hb[t & 1];
        _Float16*       hbn = hb[(t + 1) & 1];

        const half8 A0a = *(const half8*)&hbc[rslA + 8 * q];
        const half8 A1a = *(const half8*)&hbc[rslA + 32 + 8 * q];
        const half8 A0b = *(const half8*)&hbc[rslB + 8 * q];
        const half8 A1b = *(const half8*)&hbc[rslB + 32 + 8 * q];
        const half4 x4a = *(const half4*)&xt[(t * XQSTR + cnl) * 4];
        const half4 x4b = *(const half4*)&xt[(t * XQSTR + 16 + cnl) * 4];
        const half8 AXa = { x4a[0], x4a[1], x4a[2], x4a[3],
                            (_Float16)0.0f, (_Float16)0.0f, (_Float16)0.0f, (_Float16)0.0f };
        const half8 AXb = { x4b[0], x4b[1], x4b[2], x4b[3],
                            (_Float16)0.0f, (_Float16)0.0f, (_Float16)0.0f, (_Float16)0.0f };

        floatx4 accA[4], accB[4];
        #pragma unroll
        for (int g = 0; g < 4; ++g) {
            accA[g] = __builtin_amdgcn_mfma_f32_16x16x32_f16(AXa, Bf[g][2], zero4, 0, 0, 0);
            accB[g] = __builtin_amdgcn_mfma_f32_16x16x32_f16(AXb, Bf[g][2], zero4, 0, 0, 0);
            accA[g] = __builtin_amdgcn_mfma_f32_16x16x32_f16(A0a, Bf[g][0], accA[g], 0, 0, 0);
            accB[g] = __builtin_amdgcn_mfma_f32_16x16x32_f16(A0b, Bf[g][0], accB[g], 0, 0, 0);
            accA[g] = __builtin_amdgcn_mfma_f32_16x16x32_f16(A1a, Bf[g][1], accA[g], 0, 0, 0);
            accB[g] = __builtin_amdgcn_mfma_f32_16x16x32_f16(A1b, Bf[g][1], accB[g], 0, 0, 0);
        }

        #pragma unroll
        for (int r = 0; r < 4; ++r) {
            CELL_BODY_MASK(accA, r, r, wrA[r], rlA[r])
            CELL_BODY_MASK(accB, r, (4 + r), wrB[r], rlB[r])
        }
        __syncthreads();
    }

    const _Float16* hbL = hb[maxlen & 1];

    // ---- epilogue: h1 = relu(h @ W1 + b1) ----
    {
        const int j  = tid & 63;
        const int bb = tid >> 6;           // 0..3
        const float bj = b1[j];
        #pragma unroll
        for (int p = 0; p < NB / 4; ++p) {
            const int b = p * 4 + bb;
            float acc = bj;
            #pragma unroll 8
            for (int k = 0; k < UNITS; ++k)
                acc += (float)hbL[b * HSTR + k] * W1[k * 64 + j];
            h1buf[b * 64 + j] = fmaxf(acc, 0.0f);
        }
    }
    __syncthreads();

    if (tid < NB * 5) {
        const int b = tid / 5, s = tid % 5;
        float acc = b2[s];
        for (int j = 0; j < 64; ++j)
            acc += h1buf[b * 64 + j] * W2[j * 5 + s];
        logitbuf[b * 5 + s] = acc;
    }
    __syncthreads();

    if (tid < NB) {
        const int gb = b0 + tid;   // identity mapping — no permutation
        const float l0 = logitbuf[tid * 5 + 0];
        const float l1 = logitbuf[tid * 5 + 1];
        const float l2 = logitbuf[tid * 5 + 2];
        const float l3 = logitbuf[tid * 5 + 3];
        const float l4 = logitbuf[tid * 5 + 4];
        const float m  = fmaxf(fmaxf(fmaxf(l0, l1), fmaxf(l2, l3)), l4);
        const float e0 = __expf(l0 - m), e1 = __expf(l1 - m), e2 = __expf(l2 - m);
        const float e3 = __expf(l3 - m), e4 = __expf(l4 - m);
        const float rs = 1.0f / (e0 + e1 + e2 + e3 + e4);
        out[(size_t)gb * 5 + 0] = e0 * rs;
        out[(size_t)gb * 5 + 1] = e1 * rs;
        out[(size_t)gb * 5 + 2] = e2 * rs;
        out[(size_t)gb * 5 + 3] = e3 * rs;
        out[(size_t)gb * 5 + 4] = e4 * rs;
    }
#undef CELL_BODY
#undef CELL_BODY_MASK
}

extern "C" void kernel_launch(void* const* d_in, const int* in_sizes, int n_in,
                              void* d_out, int out_size, void* d_ws, size_t ws_size,
                              hipStream_t stream) {
    const float* x  = (const float*)d_in[0];
    const float* W  = (const float*)d_in[1];
    const float* U  = (const float*)d_in[2];
    const float* b  = (const float*)d_in[3];
    const float* W1 = (const float*)d_in[4];
    const float* b1 = (const float*)d_in[5];
    const float* W2 = (const float*)d_in[6];
    const float* b2 = (const float*)d_in[7];
    float* out = (float*)d_out;

    const int B = in_sizes[0] / (TT * 3);   // 16384

    lstm_kernel<<<dim3(B / NB), dim3(NTH), 0, stream>>>(
        x, W, U, b, W1, b1, W2, b2, out, B);
}

// Round 5
// 195.086 us; speedup vs baseline: 1.1055x; 1.1055x over previous
//
#include <hip/hip_runtime.h>
#include <math.h>

#define UNITS 64
#define TT 100
#define NB 16          // batch rows per tile = one MFMA M-tile
#define NTH 256        // 4 waves; wave w owns unit-columns [16w,16w+16) for all 4 gates
#define HSTR 72        // hbuf row stride in halves (identity rows: b128 reads 2-way = free)
#define XQSTR 18       // xt quad stride per timestep (16 rows + 2 pad -> conflict-free)

typedef _Float16 half8 __attribute__((ext_vector_type(8)));
typedef _Float16 half4 __attribute__((ext_vector_type(4)));
typedef float floatx4 __attribute__((ext_vector_type(4)));
typedef float floatx2 __attribute__((ext_vector_type(2)));

#define LOG2E 1.44269504088896f

__device__ __forceinline__ float rcp_fast(float x) { return __builtin_amdgcn_rcpf(x); }
__device__ __forceinline__ float exp2_fast(float x) { return __builtin_amdgcn_exp2f(x); }
__device__ __forceinline__ floatx2 fma2(floatx2 a, floatx2 b, floatx2 c) {
    return __builtin_elementwise_fma(a, b, c);
}

// Session ledger (key structural facts, do not re-derive):
//  - ONE dispatch total: extra graph nodes cost 30-75 us; cross-block sync 300-1300 us.
//  - length-sorting / load-balancing structurally dead (exactly-resident grid).
//  - r16 (8 waves via launch_bounds(512,8)) FAILED: VGPR cap 64 -> Bf spilled ->
//    1.5 GB HBM, 731 us. 4-gate-complete layout needs ~91+ VGPR headroom.
//  - r18 (NB=32, 2 waves/SIMD) FAILED: 164 us, VALUBusy 65->56. Per-wave ILP does
//    NOT substitute for TLP; 4 waves/SIMD is BOTH the ceiling (64 rows/CU /
//    16-row wave-groups) and the optimum. NB=16 / 4 blocks/CU is the structure.
//  - hslot write-permutation moved conflicts writes->reads, net zero. Write
//    conflicts (~3.6M cyc, ~4%) accepted; reads must stay clean.
//  - op-shave calibration: each removed per-cell op ~ 1.5-2 us (r15, r17).
//    Simple VALU is a big share of busy -> pack it (v_pk_*_f32), shave it.
// Round 19 (this round): r3 structure + 7-trans cell (r18-verified math) +
//  float2-packed simple math (pairs {r0,r1},{r2,r3} -> v_pk_fma/add/mul_f32),
//  trans stays scalar on components. ~26 -> ~13 simple issues per lane-step.
__global__ __launch_bounds__(NTH, 4) void lstm_kernel(
    const float* __restrict__ x,    // (B,100,3)
    const float* __restrict__ W,    // (3,256)
    const float* __restrict__ U,    // (64,256)
    const float* __restrict__ bias, // (256,)
    const float* __restrict__ W1,   // (64,64)
    const float* __restrict__ b1,   // (64,)
    const float* __restrict__ W2,   // (64,5)
    const float* __restrict__ b2,   // (5,)
    float* __restrict__ out, int B)
{
    __shared__ __align__(16) _Float16 hb[2][NB * HSTR];   // double-buffered h (f16)
    __shared__ __align__(16) _Float16 xt[TT * XQSTR * 4]; // staged x tile: quads {x0,x1,x2,1}
    __shared__ int llen_s[NB];                            // per-row lengths (this tile)
    __shared__ float h1buf[NB * 64];
    __shared__ float logitbuf[NB * 5];

    const int tid = threadIdx.x;
    const int w   = tid >> 6;
    const int l   = tid & 63;
    const int q   = l >> 4;
    const int cnl = l & 15;
    const int b0  = blockIdx.x * NB;
    const int grp = tid >> 4;   // row within tile
    const int sub = tid & 15;   // lane within row

    // ---- in-block per-row lengths: 16 lanes/row, strided, coalesced ----
    {
        const float* xp = x + (size_t)(b0 + grp) * (TT * 3);
        int m = 0;
        for (int t = sub; t < TT; t += 16) {   // 12B/lane contiguous
            const float a = xp[3*t], b = xp[3*t+1], c = xp[3*t+2];
            if (a != 0.0f || b != 0.0f || c != 0.0f) m = t + 1;
        }
        #pragma unroll
        for (int off = 8; off; off >>= 1) m = max(m, __shfl_down(m, off, 16));
        if (sub == 0) llen_s[grp] = m;
    }
    for (int i = tid; i < NB * HSTR; i += NTH) hb[0][i] = (_Float16)0.0f;
    __syncthreads();   // llen_s visible before ANY reader

    int maxlen = 0, minlen = TT;
    #pragma unroll
    for (int i = 0; i < NB; ++i) {             // LDS broadcast reads, cheap
        const int v = llen_s[i];
        maxlen = max(maxlen, v);
        minlen = min(minlen, v);
    }
    maxlen = (maxlen < 0) ? 0 : ((maxlen > TT) ? TT : maxlen);
    minlen = (minlen < 0) ? 0 : ((minlen > maxlen) ? maxlen : minlen);
    int rl[4];
    #pragma unroll
    for (int r = 0; r < 4; ++r) rl[r] = llen_s[4*q + r];

    // ---- stage x tile as f16 quads {x0,x1,x2,1} ----
    {
        const float* xp = x + (size_t)(b0 + grp) * (TT * 3);
        for (int t = sub; t < maxlen; t += 16) {
            const float a = xp[3*t], b = xp[3*t+1], c = xp[3*t+2];
            half4 v = { (_Float16)a, (_Float16)b, (_Float16)c, (_Float16)1.0f };
            *(half4*)&xt[(t * XQSTR + grp) * 4] = v;
        }
    }

    // ---- extended-K B fragments: rows 0..63=U, 64..66=W, 67=bias, 68..95=0.
    // PRESCALED: i,f,o columns by -LOG2E, g columns by -2*LOG2E:
    //   e* = exp2(acc) = exp(-z) (sig gates) / exp(-2 z_g) (g gate).
    half8 Bf[4][3];
    {
        const float gscale[4] = { -LOG2E, -LOG2E, -2.0f * LOG2E, -LOG2E };
        #pragma unroll
        for (int g = 0; g < 4; ++g) {
            const int zc = 64 * g + 16 * w + cnl;
            #pragma unroll
            for (int kb = 0; kb < 3; ++kb)
                #pragma unroll
                for (int j = 0; j < 8; ++j) {
                    const int k = 32 * kb + 8 * q + j;
                    float v = 0.0f;
                    if (k < 64)       v = U[k * 256 + zc];
                    else if (k < 67)  v = W[(k - 64) * 256 + zc];
                    else if (k == 67) v = bias[zc];
                    Bf[g][kb][j] = (_Float16)(v * gscale[g]);
                }
        }
    }

    // cell state in scaled domain: d = -2*LOG2E * c  (d(0) = 0)
    floatx2 d01 = {0.0f, 0.0f}, d23 = {0.0f, 0.0f};
    _Float16 hcur[4] = {(_Float16)0.0f, (_Float16)0.0f, (_Float16)0.0f, (_Float16)0.0f};
    const floatx4 zero4 = {0.0f, 0.0f, 0.0f, 0.0f};
    const floatx2 one2  = {1.0f, 1.0f};
    const floatx2 c2L   = {2.0f*LOG2E, 2.0f*LOG2E};
    const floatx2 cm2L  = {-2.0f*LOG2E, -2.0f*LOG2E};
    const floatx2 clamp2 = {80.0f, 80.0f};

    const int rsl = cnl * HSTR;             // identity rows: A-reads 2-way = free
    int wr[4];
    #pragma unroll
    for (int r = 0; r < 4; ++r) wr[r] = (4*q + r) * HSTR + 16*w + cnl;

    __syncthreads();   // staging + hb[0] zero visible

// 7-trans cell update on a PAIR of cells (rows R0,R0+1), packed simple math.
// DST = d01 or d23; trans ops scalar on components.
#define CELL_PAIR(R0, DST, WRV0, WRV1)                                        \
    {                                                                         \
        const floatx2 ei2 = { exp2_fast(acc[0][R0]), exp2_fast(acc[0][R0+1]) }; \
        const floatx2 ef2 = { exp2_fast(acc[1][R0]), exp2_fast(acc[1][R0+1]) }; \
        const floatx2 eg2 = { exp2_fast(acc[2][R0]), exp2_fast(acc[2][R0+1]) }; \
        const floatx2 eo2 = { exp2_fast(acc[3][R0]), exp2_fast(acc[3][R0+1]) }; \
        const floatx2 Ag2 = one2 + eg2;                                       \
        const floatx2 P2  = fma2(ei2, Ag2, Ag2);          /* (1+ei)(1+eg) */  \
        const floatx2 Af2 = one2 + ef2;                                       \
        const floatx2 R2  = P2 * Af2;                                         \
        const floatx2 tg2 = fma2(c2L, eg2, cm2L);         /* -2L(1-eg)   */   \
        const floatx2 nm2 = fma2(DST, P2, tg2 * Af2);                         \
        const floatx2 rR2 = { rcp_fast(R2[0]), rcp_fast(R2[1]) };             \
        const floatx2 dn2 = nm2 * rR2;                                        \
        DST = dn2;                                                            \
        const floatx2 dc2 = __builtin_elementwise_min(dn2, clamp2);           \
        const floatx2 ed2 = { exp2_fast(dc2[0]), exp2_fast(dc2[1]) };         \
        const floatx2 D22 = one2 + ed2;                                       \
        const floatx2 Q2  = fma2(eo2, D22, D22);          /* (1+eo)(1+ed) */  \
        const floatx2 s2  = one2 - ed2;                                       \
        const floatx2 rQ2 = { rcp_fast(Q2[0]), rcp_fast(Q2[1]) };             \
        const floatx2 hv2 = s2 * rQ2;                                         \
        hcur[R0]   = (_Float16)hv2[0];                                        \
        hcur[R0+1] = (_Float16)hv2[1];                                        \
        hbn[WRV0] = hcur[R0];                                                 \
        hbn[WRV1] = hcur[R0+1];                                               \
    }

#define CELL_PAIR_MASK(R0, DST, WRV0, WRV1, L0, L1)                           \
    {                                                                         \
        const bool lv0 = (t < L0), lv1 = (t < L1);                            \
        const floatx2 ei2 = { exp2_fast(acc[0][R0]), exp2_fast(acc[0][R0+1]) }; \
        const floatx2 ef2 = { exp2_fast(acc[1][R0]), exp2_fast(acc[1][R0+1]) }; \
        const floatx2 eg2 = { exp2_fast(acc[2][R0]), exp2_fast(acc[2][R0+1]) }; \
        const floatx2 eo2 = { exp2_fast(acc[3][R0]), exp2_fast(acc[3][R0+1]) }; \
        const floatx2 Ag2 = one2 + eg2;                                       \
        const floatx2 P2  = fma2(ei2, Ag2, Ag2);                              \
        const floatx2 Af2 = one2 + ef2;                                       \
        const floatx2 R2  = P2 * Af2;                                         \
        const floatx2 tg2 = fma2(c2L, eg2, cm2L);                             \
        const floatx2 nm2 = fma2(DST, P2, tg2 * Af2);                         \
        const floatx2 rR2 = { rcp_fast(R2[0]), rcp_fast(R2[1]) };             \
        const floatx2 dn2 = nm2 * rR2;                                        \
        DST[0] = lv0 ? dn2[0] : DST[0];                                       \
        DST[1] = lv1 ? dn2[1] : DST[1];                                       \
        const floatx2 dc2 = __builtin_elementwise_min(dn2, clamp2);           \
        const floatx2 ed2 = { exp2_fast(dc2[0]), exp2_fast(dc2[1]) };         \
        const floatx2 D22 = one2 + ed2;                                       \
        const floatx2 Q2  = fma2(eo2, D22, D22);                              \
        const floatx2 s2  = one2 - ed2;                                       \
        const floatx2 rQ2 = { rcp_fast(Q2[0]), rcp_fast(Q2[1]) };             \
        const floatx2 hv2 = s2 * rQ2;                                         \
        hcur[R0]   = lv0 ? (_Float16)hv2[0] : hcur[R0];                       \
        hcur[R0+1] = lv1 ? (_Float16)hv2[1] : hcur[R0+1];                     \
        hbn[WRV0] = hcur[R0];                                                 \
        hbn[WRV1] = hcur[R0+1];                                               \
    }

    int t = 0;

    // ---- unmasked main loop: all 16 rows live for t < minlen ----
    #pragma unroll 1
    for (; t < minlen; ++t) {
        const _Float16* hbc = hb[t & 1];
        _Float16*       hbn = hb[(t + 1) & 1];

        const half8 A0 = *(const half8*)&hbc[rsl + 8 * q];
        const half8 A1 = *(const half8*)&hbc[rsl + 32 + 8 * q];
        // all lanes read the q=0 quad (same-addr broadcast); q>=1 B-rows are zero
        const half4 x4 = *(const half4*)&xt[(t * XQSTR + cnl) * 4];
        const half8 AX = { x4[0], x4[1], x4[2], x4[3],
                           (_Float16)0.0f, (_Float16)0.0f, (_Float16)0.0f, (_Float16)0.0f };

        floatx4 acc[4];
        #pragma unroll
        for (int g = 0; g < 4; ++g) {
            acc[g] = __builtin_amdgcn_mfma_f32_16x16x32_f16(AX, Bf[g][2], zero4, 0, 0, 0);
            acc[g] = __builtin_amdgcn_mfma_f32_16x16x32_f16(A0, Bf[g][0], acc[g], 0, 0, 0);
            acc[g] = __builtin_amdgcn_mfma_f32_16x16x32_f16(A1, Bf[g][1], acc[g], 0, 0, 0);
        }

        CELL_PAIR(0, d01, wr[0], wr[1])
        CELL_PAIR(2, d23, wr[2], wr[3])
        __syncthreads();
    }

    // ---- masked tail: rows die as t reaches their length ----
    #pragma unroll 1
    for (; t < maxlen; ++t) {
        const _Float16* hbc = hb[t & 1];
        _Float16*       hbn = hb[(t + 1) & 1];

        const half8 A0 = *(const half8*)&hbc[rsl + 8 * q];
        const half8 A1 = *(const half8*)&hbc[rsl + 32 + 8 * q];
        const half4 x4 = *(const half4*)&xt[(t * XQSTR + cnl) * 4];
        const half8 AX = { x4[0], x4[1], x4[2], x4[3],
                           (_Float16)0.0f, (_Float16)0.0f, (_Float16)0.0f, (_Float16)0.0f };

        floatx4 acc[4];
        #pragma unroll
        for (int g = 0; g < 4; ++g) {
            acc[g] = __builtin_amdgcn_mfma_f32_16x16x32_f16(AX, Bf[g][2], zero4, 0, 0, 0);
            acc[g] = __builtin_amdgcn_mfma_f32_16x16x32_f16(A0, Bf[g][0], acc[g], 0, 0, 0);
            acc[g] = __builtin_amdgcn_mfma_f32_16x16x32_f16(A1, Bf[g][1], acc[g], 0, 0, 0);
        }

        CELL_PAIR_MASK(0, d01, wr[0], wr[1], rl[0], rl[1])
        CELL_PAIR_MASK(2, d23, wr[2], wr[3], rl[2], rl[3])
        __syncthreads();
    }

    const _Float16* hbL = hb[maxlen & 1];

    // ---- epilogue: h1 = relu(h @ W1 + b1) ----
    {
        const int j  = tid & 63;
        const int bb = tid >> 6;
        const float bj = b1[j];
        #pragma unroll
        for (int p = 0; p < NB / 4; ++p) {
            const int b = p * 4 + bb;
            float acc = bj;
            #pragma unroll 8
            for (int k = 0; k < UNITS; ++k)
                acc += (float)hbL[b * HSTR + k] * W1[k * 64 + j];
            h1buf[b * 64 + j] = fmaxf(acc, 0.0f);
        }
    }
    __syncthreads();

    if (tid < NB * 5) {
        const int b = tid / 5, s = tid % 5;
        float acc = b2[s];
        for (int j = 0; j < 64; ++j)
            acc += h1buf[b * 64 + j] * W2[j * 5 + s];
        logitbuf[b * 5 + s] = acc;
    }
    __syncthreads();

    if (tid < NB) {
        const int gb = b0 + tid;   // identity mapping — no permutation
        const float l0 = logitbuf[tid * 5 + 0];
        const float l1 = logitbuf[tid * 5 + 1];
        const float l2 = logitbuf[tid * 5 + 2];
        const float l3 = logitbuf[tid * 5 + 3];
        const float l4 = logitbuf[tid * 5 + 4];
        const float m  = fmaxf(fmaxf(fmaxf(l0, l1), fmaxf(l2, l3)), l4);
        const float e0 = __expf(l0 - m), e1 = __expf(l1 - m), e2 = __expf(l2 - m);
        const float e3 = __expf(l3 - m), e4 = __expf(l4 - m);
        const float rs = 1.0f / (e0 + e1 + e2 + e3 + e4);
        out[(size_t)gb * 5 + 0] = e0 * rs;
        out[(size_t)gb * 5 + 1] = e1 * rs;
        out[(size_t)gb * 5 + 2] = e2 * rs;
        out[(size_t)gb * 5 + 3] = e3 * rs;
        out[(size_t)gb * 5 + 4] = e4 * rs;
    }
#undef CELL_PAIR
#undef CELL_PAIR_MASK
}

extern "C" void kernel_launch(void* const* d_in, const int* in_sizes, int n_in,
                              void* d_out, int out_size, void* d_ws, size_t ws_size,
                              hipStream_t stream) {
    const float* x  = (const float*)d_in[0];
    const float* W  = (const float*)d_in[1];
    const float* U  = (const float*)d_in[2];
    const float* b  = (const float*)d_in[3];
    const float* W1 = (const float*)d_in[4];
    const float* b1 = (const float*)d_in[5];
    const float* W2 = (const float*)d_in[6];
    const float* b2 = (const float*)d_in[7];
    float* out = (float*)d_out;

    const int B = in_sizes[0] / (TT * 3);   // 16384

    lstm_kernel<<<dim3(B / NB), dim3(NTH), 0, stream>>>(
        x, W, U, b, W1, b1, W2, b2, out, B);
}